// Round 1
// baseline (695.814 us; speedup 1.0000x reference)
//
#include <hip/hip_runtime.h>
#include <hip/hip_bf16.h>

// MambaMinimalBlock: B=4, L=2048, D_MODEL=1024, D_STATE=16, D_CONV=4,
// D_INNER=2048, BL=8192. fp32 in/out.
//
// R12: (a) GEMM staging reg->LDS replaced with global_load_lds width=16
// (m151: 874 vs 646 TF at same 128^2 tile). Linear LDS dest + inverse-
// swizzled global source + unchanged swizzled ds_read (rule #21) keeps
// the R10 zero-bank-conflict LDS image bit-identical.
// (b) Scan: O(NCHK^2) in-pass2 fold hoisted into scan_fold (sequential
// prefix over chunk summaries, in-place into SUMH), NCHK 32->64 for 2x
// scan parallelism (R11 counters: occupancy 21%, VALUBusy 45% = latency
// bound, fold was the regression source 110->127us).
//
// GEMMs: plain bf16 MFMA (fp32 acc). bc: split-K MFMA with hi/lo weight
// split. absmax prev 1.95e-3 vs 5.59e-3 threshold.

typedef float  f32x4  __attribute__((ext_vector_type(4)));
typedef short  bf16x8 __attribute__((ext_vector_type(8)));

#define NCHK 64
#define CLEN 32
#define SW   8      // scan window (double-buffered)

__device__ __forceinline__ ushort f2bf(float f) {
    uint u = __float_as_uint(f);
    u += 0x7FFF + ((u >> 16) & 1);          // RNE
    return (ushort)(u >> 16);
}
__device__ __forceinline__ float bf2f(ushort h) {
    return __uint_as_float((uint)h << 16);
}
__device__ __forceinline__ float softplus_f(float x) {
    return fmaxf(x, 0.f) + __logf(1.f + __expf(-fabsf(x)));
}
__device__ __forceinline__ float silu_f(float x) {
    return x / (1.f + __expf(-x));
}

// swizzled LDS chunk address (ushort units): row stride 32, chunk q
// permuted by row: slot c = (q + (row>>1)) & 3.
__device__ __forceinline__ int lds_addr(int row, int q) {
    return (row << 5) + ((((q + (row >> 1)) & 3)) << 3);
}
__device__ __forceinline__ int lds_frag_off(int lane) {
    const int r = lane & 15, q = lane >> 4;
    return (r << 5) + ((((q + (r >> 1)) & 3)) << 3);
}

// async global->LDS, 16B per lane; LDS dest = wave-uniform base + lane*16.
__device__ __forceinline__ void gload16(const ushort* g, ushort* l) {
    __builtin_amdgcn_global_load_lds(
        (const __attribute__((address_space(1))) void*)g,
        (__attribute__((address_space(3))) void*)l,
        16, 0, 0);
}

__global__ __launch_bounds__(256)
void split_w_kernel(const float* __restrict__ src, ushort* __restrict__ hi,
                    ushort* __restrict__ lo)
{
    const int i = blockIdx.x * 256 + threadIdx.x;
    float4 v = ((const float4*)src)[i];
    ushort4 h, l;
    h.x = f2bf(v.x); l.x = f2bf(v.x - bf2f(h.x));
    h.y = f2bf(v.y); l.y = f2bf(v.y - bf2f(h.y));
    h.z = f2bf(v.z); l.z = f2bf(v.z - bf2f(h.z));
    h.w = f2bf(v.w); l.w = f2bf(v.w - bf2f(h.w));
    ((ushort4*)hi)[i] = h;
    ((ushort4*)lo)[i] = l;
}

__global__ __launch_bounds__(256)
void cvt_bf16_kernel(const float* __restrict__ src, ushort* __restrict__ dst)
{
    const int i = blockIdx.x * 256 + threadIdx.x;
    float4 v = ((const float4*)src)[i];
    ushort4 h;
    h.x = f2bf(v.x); h.y = f2bf(v.y); h.z = f2bf(v.z); h.w = f2bf(v.w);
    ((ushort4*)dst)[i] = h;
}

// C[M,N] = A[M,K](bf16) * B[N,K]^T(bf16), fp32 accumulate.
// 128x128 block, 4 waves x (4x4 of 16x16x32 MFMA). global_load_lds
// staging (linear dest); source chunk index inverse-swizzled so the LDS
// image matches lds_addr(); fragment reads unchanged (zero conflicts).
// EPI: 0 = fp32 store, 1 = softplus(v + bias[col]) fp32, 2 = bf16 store.
template <int EPI>
__global__ __launch_bounds__(256)
void gemm_mfma(const ushort* __restrict__ A, const ushort* __restrict__ Bm,
               const float* __restrict__ bias, void* __restrict__ Cout,
               int N, int K)
{
    __shared__ __attribute__((aligned(16))) ushort As[4096];   // 8 KB
    __shared__ __attribute__((aligned(16))) ushort Bs[4096];   // 8 KB

    const int tid  = threadIdx.x;
    const int lane = tid & 63;
    const int wave = tid >> 6;
    const int wm   = (wave >> 1) * 64;
    const int wn   = (wave & 1) * 64;
    const int row0 = blockIdx.y * 128;
    const int col0 = blockIdx.x * 128;

    // staging: lane t writes LDS bytes j*4096 + t*16 (rows j*64 + t/4,
    // slot t&3). Slot c must hold global chunk q = (c - (row>>1)) & 3.
    const int crow = tid >> 2;            // 0..63 (row within half-tile)
    const int cq   = tid & 3;             // LDS slot
    const int qsrc = (cq - (crow >> 1)) & 3;   // global 16B chunk to fetch
    const ushort* Ag0 = A  + (size_t)(row0 + crow) * K + qsrc * 8;
    const ushort* Ag1 = A  + (size_t)(row0 + crow + 64) * K + qsrc * 8;
    const ushort* Bg0 = Bm + (size_t)(col0 + crow) * K + qsrc * 8;
    const ushort* Bg1 = Bm + (size_t)(col0 + crow + 64) * K + qsrc * 8;

    ushort* lA0 = As + wave * 512;          // j=0, bytes wave*1024
    ushort* lA1 = As + 2048 + wave * 512;   // j=1, +4096B
    ushort* lB0 = Bs + wave * 512;
    ushort* lB1 = Bs + 2048 + wave * 512;

    const int flo = lds_frag_off(lane);
    const int fra = (wm << 5) + flo;
    const int frb = (wn << 5) + flo;

    f32x4 acc[4][4];
#pragma unroll
    for (int mi = 0; mi < 4; ++mi)
#pragma unroll
        for (int ni = 0; ni < 4; ++ni)
            acc[mi][ni] = (f32x4){0.f, 0.f, 0.f, 0.f};

    for (int k0 = 0; k0 < K; k0 += 32) {
        __syncthreads();
        gload16(Ag0 + k0, lA0);
        gload16(Ag1 + k0, lA1);
        gload16(Bg0 + k0, lB0);
        gload16(Bg1 + k0, lB1);
        __syncthreads();
        bf16x8 af[4], bf[4];
#pragma unroll
        for (int mi = 0; mi < 4; ++mi)
            af[mi] = *(const bf16x8*)(As + fra + mi * 512);
#pragma unroll
        for (int ni = 0; ni < 4; ++ni)
            bf[ni] = *(const bf16x8*)(Bs + frb + ni * 512);
#pragma unroll
        for (int mi = 0; mi < 4; ++mi)
#pragma unroll
            for (int ni = 0; ni < 4; ++ni)
                acc[mi][ni] = __builtin_amdgcn_mfma_f32_16x16x32_bf16(
                    af[mi], bf[ni], acc[mi][ni], 0, 0, 0);
    }

#pragma unroll
    for (int mi = 0; mi < 4; ++mi) {
        const int rg = row0 + wm + mi * 16 + (lane >> 4) * 4;
#pragma unroll
        for (int ni = 0; ni < 4; ++ni) {
            const int cg = col0 + wn + ni * 16 + (lane & 15);
            f32x4 v = acc[mi][ni];
            if (EPI == 1) {
                const float bv = bias[cg];
#pragma unroll
                for (int r = 0; r < 4; ++r) v[r] = softplus_f(v[r] + bv);
            }
#pragma unroll
            for (int r = 0; r < 4; ++r) {
                if (EPI == 2)
                    ((ushort*)Cout)[(size_t)(rg + r) * N + cg] = f2bf(v[r]);
                else
                    ((float*)Cout)[(size_t)(rg + r) * N + cg] = v[r];
            }
        }
    }
}

// Split-K bc GEMM: part[ks] = xc[:, ks*256:(ks+1)*256] @ Wx^T slice.
__global__ __launch_bounds__(256)
void gemm_bc_mfma(const ushort* __restrict__ A, const ushort* __restrict__ Bh,
                  const ushort* __restrict__ Bl, float* __restrict__ part)
{
    __shared__ __attribute__((aligned(16))) ushort As[4096];
    __shared__ __attribute__((aligned(16))) ushort Bhs[1024];
    __shared__ __attribute__((aligned(16))) ushort Bls[1024];

    const int tid  = threadIdx.x;
    const int lane = tid & 63;
    const int wave = tid >> 6;
    const int ks   = blockIdx.x;     // 0..7
    const int mb   = blockIdx.y;     // 0..63
    const int row0 = mb * 128;
    const int kb   = ks * 256;

    const int crow = tid >> 2;
    const int cq   = tid & 3;
    const ushort* Ag0 = A + (size_t)(row0 + crow) * 2048 + kb + cq * 8;
    const ushort* Ag1 = A + (size_t)(row0 + crow + 64) * 2048 + kb + cq * 8;
    const int st0 = lds_addr(crow, cq);
    const int st1 = st0 + 2048;

    const int t2   = tid & 127;
    const int brow = t2 >> 2;        // 0..31
    const int bq   = t2 & 3;
    const ushort* Bg = (tid < 128 ? Bh : Bl) + (size_t)brow * 2048 + kb + bq * 8;
    ushort* Bdst     = (tid < 128 ? Bhs : Bls) + lds_addr(brow, bq);

    const int wm  = wave * 32;
    const int flo = lds_frag_off(lane);
    const int fra = (wm << 5) + flo;
    const int frb = flo;

    f32x4 acc[2][2];
#pragma unroll
    for (int mi = 0; mi < 2; ++mi)
#pragma unroll
        for (int ni = 0; ni < 2; ++ni)
            acc[mi][ni] = (f32x4){0.f, 0.f, 0.f, 0.f};

    uint4 ra0 = *(const uint4*)Ag0, ra1 = *(const uint4*)Ag1;
    uint4 rb  = *(const uint4*)Bg;

    for (int kt = 0; kt < 8; ++kt) {
        __syncthreads();
        *(uint4*)(As + st0) = ra0;
        *(uint4*)(As + st1) = ra1;
        *(uint4*)Bdst = rb;
        __syncthreads();
        if (kt < 7) {
            ra0 = *(const uint4*)(Ag0 + (kt + 1) * 32);
            ra1 = *(const uint4*)(Ag1 + (kt + 1) * 32);
            rb  = *(const uint4*)(Bg + (kt + 1) * 32);
        }
        bf16x8 af[2], bhf[2], blf[2];
#pragma unroll
        for (int mi = 0; mi < 2; ++mi)
            af[mi] = *(const bf16x8*)(As + fra + mi * 512);
#pragma unroll
        for (int ni = 0; ni < 2; ++ni) {
            bhf[ni] = *(const bf16x8*)(Bhs + frb + ni * 512);
            blf[ni] = *(const bf16x8*)(Bls + frb + ni * 512);
        }
#pragma unroll
        for (int mi = 0; mi < 2; ++mi)
#pragma unroll
            for (int ni = 0; ni < 2; ++ni) {
                acc[mi][ni] = __builtin_amdgcn_mfma_f32_16x16x32_bf16(
                    af[mi], bhf[ni], acc[mi][ni], 0, 0, 0);
                acc[mi][ni] = __builtin_amdgcn_mfma_f32_16x16x32_bf16(
                    af[mi], blf[ni], acc[mi][ni], 0, 0, 0);
            }
    }

#pragma unroll
    for (int mi = 0; mi < 2; ++mi) {
        const int rg = row0 + wm + mi * 16 + (lane >> 4) * 4;
#pragma unroll
        for (int ni = 0; ni < 2; ++ni) {
            const int cg = ni * 16 + (lane & 15);
            f32x4 v = acc[mi][ni];
#pragma unroll
            for (int r = 0; r < 4; ++r)
                part[((size_t)ks * 8192 + rg + r) * 32 + cg] = v[r];
        }
    }
}

__global__ __launch_bounds__(256)
void bc_reduce_kernel(const float* __restrict__ part, float* __restrict__ bc)
{
    const int i = blockIdx.x * 256 + threadIdx.x;   // 262144
    float s = 0.f;
#pragma unroll
    for (int ks = 0; ks < 8; ++ks)
        s += part[(size_t)ks * 262144 + i];
    bc[i] = s;
}

// Depthwise causal conv1d (4 taps) + bias + silu; bf16 in, bf16 out.
__global__ __launch_bounds__(256)
void conv_silu_kernel(const ushort* __restrict__ xi, const float* __restrict__ cw,
                      const float* __restrict__ cb, ushort* __restrict__ xc)
{
    const int idx = blockIdx.x * 256 + threadIdx.x;
    const int e   = (idx & 511) << 2;
    const int row = idx >> 9;
    const int l   = row & 2047;

    const float4 w0 = *(const float4*)(cw + (size_t)(e + 0) * 4);
    const float4 w1 = *(const float4*)(cw + (size_t)(e + 1) * 4);
    const float4 w2 = *(const float4*)(cw + (size_t)(e + 2) * 4);
    const float4 w3 = *(const float4*)(cw + (size_t)(e + 3) * 4);

    float4 acc = *(const float4*)(cb + e);

#define CONV_TAP(K_, WSEL)                                                  \
    {                                                                       \
        ushort4 t = *(const ushort4*)(xi + (size_t)(row - (K_)) * 2048 + e);\
        acc.x = fmaf(bf2f(t.x), w0.WSEL, acc.x);                            \
        acc.y = fmaf(bf2f(t.y), w1.WSEL, acc.y);                            \
        acc.z = fmaf(bf2f(t.z), w2.WSEL, acc.z);                            \
        acc.w = fmaf(bf2f(t.w), w3.WSEL, acc.w);                            \
    }
    if (l >= 3) CONV_TAP(3, x)
    if (l >= 2) CONV_TAP(2, y)
    if (l >= 1) CONV_TAP(1, z)
    CONV_TAP(0, w)
#undef CONV_TAP

    ushort4 o;
    o.x = f2bf(silu_f(acc.x)); o.y = f2bf(silu_f(acc.y));
    o.z = f2bf(silu_f(acc.z)); o.w = f2bf(silu_f(acc.w));
    *(ushort4*)(xc + (size_t)row * 2048 + e) = o;
}

// ---- d-parallel chunked selective scan (NCHK chunks of CLEN) ----

// Pass 1: chunks 0..NCHK-2, h from 0, writes he + P = exp(A * sum dt).
__global__ __launch_bounds__(256)
void scan_part1(const ushort* __restrict__ xcb, const float* __restrict__ dbuf,
                const float* __restrict__ bcbuf, const float* __restrict__ A_log,
                float* __restrict__ sum_h, float* __restrict__ sum_p)
{
    const int c    = blockIdx.x >> 5;          // 0..NCHK-2
    const int b    = (blockIdx.x >> 3) & 3;
    const int dblk = blockIdx.x & 7;
    const int d    = dblk * 256 + threadIdx.x;

    float Aval[16];
#pragma unroll
    for (int q = 0; q < 4; ++q) {
        float4 al = *(const float4*)(A_log + (size_t)d * 16 + q * 4);
        Aval[q*4+0] = -__expf(al.x); Aval[q*4+1] = -__expf(al.y);
        Aval[q*4+2] = -__expf(al.z); Aval[q*4+3] = -__expf(al.w);
    }

    const size_t row0 = (size_t)b * 2048 + (size_t)c * CLEN;
    const float*  dp  = dbuf + row0 * 2048 + d;
    const ushort* xp  = xcb  + row0 * 2048 + d;
    const float*  bcp = bcbuf + row0 * 32;

    float h[16];
#pragma unroll
    for (int s = 0; s < 16; ++s) h[s] = 0.f;
    float S = 0.f;

    float wdt[SW], wxv[SW];
#pragma unroll
    for (int j = 0; j < SW; ++j) {
        wdt[j] = dp[(size_t)j * 2048];
        wxv[j] = bf2f(xp[(size_t)j * 2048]);
    }
    float curB[16];
#pragma unroll
    for (int q = 0; q < 4; ++q)
        *(float4*)&curB[q*4] = *(const float4*)(bcp + q * 4);

    for (int l0 = 0; l0 < CLEN; l0 += SW) {
        float ndt[SW], nxv[SW];
        const bool more = (l0 + SW) < CLEN;
        if (more) {
#pragma unroll
            for (int j = 0; j < SW; ++j) {
                const size_t o = (size_t)(l0 + SW + j);
                ndt[j] = dp[o * 2048];
                nxv[j] = bf2f(xp[o * 2048]);
            }
        }
#pragma unroll
        for (int j = 0; j < SW; ++j) {
            const int l = l0 + j;
            float nB[16];
            if (l + 1 < CLEN) {
#pragma unroll
                for (int q = 0; q < 4; ++q)
                    *(float4*)&nB[q*4] = *(const float4*)(bcp + (size_t)(l+1) * 32 + q * 4);
            }
            const float dt = wdt[j];
            const float t  = dt * wxv[j];
            S += dt;
#pragma unroll
            for (int s = 0; s < 16; ++s)
                h[s] = __expf(dt * Aval[s]) * h[s] + curB[s] * t;
            if (l + 1 < CLEN) {
#pragma unroll
                for (int s = 0; s < 16; ++s) curB[s] = nB[s];
            }
        }
        if (more) {
#pragma unroll
            for (int j = 0; j < SW; ++j) { wdt[j] = ndt[j]; wxv[j] = nxv[j]; }
        }
    }

    float* sh = sum_h + ((((size_t)c * 4 + b) * 2048 + d) << 4);
    float* sp = sum_p + ((((size_t)c * 4 + b) * 2048 + d) << 4);
#pragma unroll
    for (int q = 0; q < 4; ++q) {
        *(float4*)(sh + q * 4) = make_float4(h[q*4], h[q*4+1], h[q*4+2], h[q*4+3]);
        *(float4*)(sp + q * 4) = make_float4(__expf(Aval[q*4] * S), __expf(Aval[q*4+1] * S),
                                             __expf(Aval[q*4+2] * S), __expf(Aval[q*4+3] * S));
    }
}

// Sequential prefix over chunk summaries, in-place into sum_h.
// After: sum_h slot c holds the scan state at the START of chunk c+1.
// Grid: 32 blocks (4 b x 8 dblk) x 256 threads; 63 dependent steps.
__global__ __launch_bounds__(256)
void scan_fold(float* __restrict__ sum_h, const float* __restrict__ sum_p)
{
    const int b = blockIdx.x >> 3;
    const int d = (blockIdx.x & 7) * 256 + threadIdx.x;

    float h[16];
#pragma unroll
    for (int s = 0; s < 16; ++s) h[s] = 0.f;

    for (int c = 0; c < NCHK - 1; ++c) {
        float*       sh = sum_h + ((((size_t)c * 4 + b) * 2048 + d) << 4);
        const float* sp = sum_p + ((((size_t)c * 4 + b) * 2048 + d) << 4);
#pragma unroll
        for (int q = 0; q < 4; ++q) {
            float4 vh = *(const float4*)(sh + q * 4);
            float4 vp = *(const float4*)(sp + q * 4);
            h[q*4+0] = vh.x + vp.x * h[q*4+0];
            h[q*4+1] = vh.y + vp.y * h[q*4+1];
            h[q*4+2] = vh.z + vp.z * h[q*4+2];
            h[q*4+3] = vh.w + vp.w * h[q*4+3];
        }
#pragma unroll
        for (int q = 0; q < 4; ++q)
            *(float4*)(sh + q * 4) = make_float4(h[q*4], h[q*4+1], h[q*4+2], h[q*4+3]);
    }
}

// Pass 2: all NCHK chunks; load start state (sum_h[c-1]), scan, y bf16 out.
__global__ __launch_bounds__(256)
void scan_part2(const ushort* __restrict__ zbuf, const ushort* __restrict__ xcb,
                const float* __restrict__ dbuf, const float* __restrict__ bcbuf,
                const float* __restrict__ A_log, const float* __restrict__ Dp,
                const float* __restrict__ sum_h, ushort* __restrict__ ybuf)
{
    const int c    = blockIdx.x >> 5;          // 0..NCHK-1
    const int b    = (blockIdx.x >> 3) & 3;
    const int dblk = blockIdx.x & 7;
    const int d    = dblk * 256 + threadIdx.x;

    float Aval[16];
#pragma unroll
    for (int q = 0; q < 4; ++q) {
        float4 al = *(const float4*)(A_log + (size_t)d * 16 + q * 4);
        Aval[q*4+0] = -__expf(al.x); Aval[q*4+1] = -__expf(al.y);
        Aval[q*4+2] = -__expf(al.z); Aval[q*4+3] = -__expf(al.w);
    }
    const float Dv = Dp[d];

    float h[16];
    if (c == 0) {
#pragma unroll
        for (int s = 0; s < 16; ++s) h[s] = 0.f;
    } else {
        const float* sh = sum_h + ((((size_t)(c - 1) * 4 + b) * 2048 + d) << 4);
#pragma unroll
        for (int q = 0; q < 4; ++q)
            *(float4*)&h[q*4] = *(const float4*)(sh + q * 4);
    }

    const size_t row0 = (size_t)b * 2048 + (size_t)c * CLEN;
    const float*  dp  = dbuf + row0 * 2048 + d;
    const ushort* xp  = xcb  + row0 * 2048 + d;
    const ushort* zp  = zbuf + row0 * 2048 + d;
    const float*  bcp = bcbuf + row0 * 32;
    ushort*       yp  = ybuf + row0 * 2048 + d;

    float wdt[SW], wxv[SW], wzv[SW];
#pragma unroll
    for (int j = 0; j < SW; ++j) {
        wdt[j] = dp[(size_t)j * 2048];
        wxv[j] = bf2f(xp[(size_t)j * 2048]);
        wzv[j] = bf2f(zp[(size_t)j * 2048]);
    }
    float curB[16], curC[16];
#pragma unroll
    for (int q = 0; q < 4; ++q) {
        *(float4*)&curB[q*4] = *(const float4*)(bcp + q * 4);
        *(float4*)&curC[q*4] = *(const float4*)(bcp + 16 + q * 4);
    }

    for (int l0 = 0; l0 < CLEN; l0 += SW) {
        float ndt[SW], nxv[SW], nzv[SW];
        const bool more = (l0 + SW) < CLEN;
        if (more) {
#pragma unroll
            for (int j = 0; j < SW; ++j) {
                const size_t o = (size_t)(l0 + SW + j);
                ndt[j] = dp[o * 2048];
                nxv[j] = bf2f(xp[o * 2048]);
                nzv[j] = bf2f(zp[o * 2048]);
            }
        }
#pragma unroll
        for (int j = 0; j < SW; ++j) {
            const int l = l0 + j;
            float nB[16], nC[16];
            if (l + 1 < CLEN) {
#pragma unroll
                for (int q = 0; q < 4; ++q) {
                    *(float4*)&nB[q*4] = *(const float4*)(bcp + (size_t)(l+1) * 32 + q * 4);
                    *(float4*)&nC[q*4] = *(const float4*)(bcp + (size_t)(l+1) * 32 + 16 + q * 4);
                }
            }
            const float dt = wdt[j];
            const float t  = dt * wxv[j];
#pragma unroll
            for (int s = 0; s < 16; ++s)
                h[s] = __expf(dt * Aval[s]) * h[s] + curB[s] * t;
            float y0 = 0.f, y1 = 0.f, y2 = 0.f, y3 = 0.f;
#pragma unroll
            for (int s = 0; s < 16; s += 4) {
                y0 = fmaf(h[s+0], curC[s+0], y0);
                y1 = fmaf(h[s+1], curC[s+1], y1);
                y2 = fmaf(h[s+2], curC[s+2], y2);
                y3 = fmaf(h[s+3], curC[s+3], y3);
            }
            float y = (y0 + y1) + (y2 + y3) + Dv * wxv[j];
            yp[(size_t)l * 2048] = f2bf(y * silu_f(wzv[j]));
            if (l + 1 < CLEN) {
#pragma unroll
                for (int s = 0; s < 16; ++s) { curB[s] = nB[s]; curC[s] = nC[s]; }
            }
        }
        if (more) {
#pragma unroll
            for (int j = 0; j < SW; ++j) {
                wdt[j] = ndt[j]; wxv[j] = nxv[j]; wzv[j] = nzv[j];
            }
        }
    }
}

extern "C" void kernel_launch(void* const* d_in, const int* in_sizes, int n_in,
                              void* d_out, int out_size, void* d_ws, size_t ws_size,
                              hipStream_t stream)
{
    const float* x          = (const float*)d_in[0];
    const float* in_proj_w  = (const float*)d_in[1];
    const float* conv_w     = (const float*)d_in[2];
    const float* conv_b     = (const float*)d_in[3];
    const float* x_proj_w   = (const float*)d_in[4];
    const float* dt_proj_w  = (const float*)d_in[5];
    const float* dt_proj_b  = (const float*)d_in[6];
    const float* A_log      = (const float*)d_in[7];
    const float* Dp         = (const float*)d_in[8];
    const float* out_proj_w = (const float*)d_in[9];
    float* out = (float*)d_out;

    // Workspace (~253 MiB of 256 MiB)
    ushort* XI    = (ushort*)d_ws;                    // 32 MB; later Y'
    ushort* Z     = XI + 16777216;                    // 32 MB
    ushort* XC2   = Z + 16777216;                     // 32 MB
    float*  DELTA = (float*)(XC2 + 16777216);         // 64 MB
    ushort* XP    = (ushort*)DELTA;                   // x' bf16 (pre-DELTA)
    ushort* WINH  = (ushort*)(DELTA + 16777216);      // 8 MB [4096,1024] bf16
    ushort* WDTH  = WINH + 4194304;                   // 8 MB [2048,2048] bf16
    ushort* WOUTH = WDTH + 4194304;                   // 4 MB [1024,2048] bf16
    float*  BC    = (float*)(WOUTH + 2097152);        // 1 MB
    float*  SUMH  = BC + 262144;                      // 33.5 MB (64*4*2048*16)
    float*  SUMP  = SUMH + 8388608;                   // 33.5 MB
    ushort* XPH   = (ushort*)(SUMP + 8388608);        // 128 KB (x_proj hi)
    ushort* XPL   = XPH + 65536;                      // 128 KB
    float*  PART  = (float*)(XPL + 65536);            // 8 MB split-K partials
    ushort* Yp    = XI;

    const dim3 blk(256);

    // 0) conversions (weights plain bf16 except x_proj hi/lo)
    cvt_bf16_kernel<<<dim3(8192), blk, 0, stream>>>(x, XP);
    cvt_bf16_kernel<<<dim3(4096), blk, 0, stream>>>(in_proj_w, WINH);
    cvt_bf16_kernel<<<dim3(4096), blk, 0, stream>>>(dt_proj_w, WDTH);
    cvt_bf16_kernel<<<dim3(2048), blk, 0, stream>>>(out_proj_w, WOUTH);
    split_w_kernel<<<dim3(64),    blk, 0, stream>>>(x_proj_w, XPH, XPL);

    // 1) xi, z
    gemm_mfma<2><<<dim3(16, 64), blk, 0, stream>>>(XP, WINH, nullptr, XI, 2048, 1024);
    gemm_mfma<2><<<dim3(16, 64), blk, 0, stream>>>(XP, WINH + 2097152, nullptr, Z, 2048, 1024);

    // 2) xc = silu(conv(xi) + b)
    conv_silu_kernel<<<dim3(16384), blk, 0, stream>>>(XI, conv_w, conv_b, XC2);

    // 3) delta = softplus(xc @ Wdt^T + b)
    gemm_mfma<1><<<dim3(16, 64), blk, 0, stream>>>(XC2, WDTH, dt_proj_b, DELTA, 2048, 2048);

    // 4) bc = xc @ x_proj_w^T  (split-K MFMA + reduce)
    gemm_bc_mfma<<<dim3(8, 64), blk, 0, stream>>>(XC2, XPH, XPL, PART);
    bc_reduce_kernel<<<dim3(1024), blk, 0, stream>>>(PART, BC);

    // 5) chunked scan: pass1 -> prefix fold -> pass2
    scan_part1<<<dim3((NCHK - 1) * 32), blk, 0, stream>>>(XC2, DELTA, BC, A_log, SUMH, SUMP);
    scan_fold<<<dim3(32), blk, 0, stream>>>(SUMH, SUMP);
    scan_part2<<<dim3(NCHK * 32), blk, 0, stream>>>(Z, XC2, DELTA, BC, A_log, Dp,
                                                    SUMH, Yp);

    // 6) out = y @ Wout^T
    gemm_mfma<0><<<dim3(8, 64), blk, 0, stream>>>(Yp, WOUTH, nullptr, out, 1024, 2048);
}

// Round 2
// 619.807 us; speedup vs baseline: 1.1226x; 1.1226x over previous
//
#include <hip/hip_runtime.h>
#include <hip/hip_bf16.h>

// MambaMinimalBlock: B=4, L=2048, D_MODEL=1024, D_STATE=16, D_CONV=4,
// D_INNER=2048, BL=8192. fp32 in/out.
//
// R13: (a) GEMM global_load_lds now DOUBLE-BUFFERED (T3 2-phase recipe):
// stage tile k+1 into buf^1 while MFMA runs on buf; one barrier/K-step.
// R12's serialized version (stage -> drain -> compute, MfmaUtil 22.5%,
// 541 TF) exposed full load latency; prefetch is what makes gload_lds
// win (m151: 874 vs 646 TF).
// (b) Scan: NCHK back to 32 (CLEN 64; 64-chunk split regressed via
// prologue amortization + 2x summary traffic), fold stays hoisted
// (scan_fold), and the per-chunk B/C panel (8 KB) is cooperatively
// staged into LDS: kills the depth-1 L2 dependent loads (~200cyc, R10
// diagnosis) and the 16-32 v_mov/step shadow-register copies.
//
// GEMMs: bf16 MFMA fp32 acc, inverse-swizzled gload source + swizzled
// ds_read (zero bank conflicts, R12-verified). bc: split-K hi/lo MFMA.
// absmax 1.95e-3 vs 5.59e-3 threshold (arithmetic unchanged from R12).

typedef float  f32x4  __attribute__((ext_vector_type(4)));
typedef short  bf16x8 __attribute__((ext_vector_type(8)));

#define NCHK 32
#define CLEN 64
#define SW   8      // scan window (double-buffered)

__device__ __forceinline__ ushort f2bf(float f) {
    uint u = __float_as_uint(f);
    u += 0x7FFF + ((u >> 16) & 1);          // RNE
    return (ushort)(u >> 16);
}
__device__ __forceinline__ float bf2f(ushort h) {
    return __uint_as_float((uint)h << 16);
}
__device__ __forceinline__ float softplus_f(float x) {
    return fmaxf(x, 0.f) + __logf(1.f + __expf(-fabsf(x)));
}
__device__ __forceinline__ float silu_f(float x) {
    return x / (1.f + __expf(-x));
}

// swizzled LDS chunk address (ushort units): row stride 32, chunk q
// permuted by row: slot c = (q + (row>>1)) & 3.
__device__ __forceinline__ int lds_addr(int row, int q) {
    return (row << 5) + ((((q + (row >> 1)) & 3)) << 3);
}
__device__ __forceinline__ int lds_frag_off(int lane) {
    const int r = lane & 15, q = lane >> 4;
    return (r << 5) + ((((q + (r >> 1)) & 3)) << 3);
}

// async global->LDS, 16B per lane; LDS dest = wave-uniform base + lane*16.
__device__ __forceinline__ void gload16(const ushort* g, ushort* l) {
    __builtin_amdgcn_global_load_lds(
        (const __attribute__((address_space(1))) void*)g,
        (__attribute__((address_space(3))) void*)l,
        16, 0, 0);
}

__global__ __launch_bounds__(256)
void split_w_kernel(const float* __restrict__ src, ushort* __restrict__ hi,
                    ushort* __restrict__ lo)
{
    const int i = blockIdx.x * 256 + threadIdx.x;
    float4 v = ((const float4*)src)[i];
    ushort4 h, l;
    h.x = f2bf(v.x); l.x = f2bf(v.x - bf2f(h.x));
    h.y = f2bf(v.y); l.y = f2bf(v.y - bf2f(h.y));
    h.z = f2bf(v.z); l.z = f2bf(v.z - bf2f(h.z));
    h.w = f2bf(v.w); l.w = f2bf(v.w - bf2f(h.w));
    ((ushort4*)hi)[i] = h;
    ((ushort4*)lo)[i] = l;
}

__global__ __launch_bounds__(256)
void cvt_bf16_kernel(const float* __restrict__ src, ushort* __restrict__ dst)
{
    const int i = blockIdx.x * 256 + threadIdx.x;
    float4 v = ((const float4*)src)[i];
    ushort4 h;
    h.x = f2bf(v.x); h.y = f2bf(v.y); h.z = f2bf(v.z); h.w = f2bf(v.w);
    ((ushort4*)dst)[i] = h;
}

// C[M,N] = A[M,K](bf16) * B[N,K]^T(bf16), fp32 accumulate.
// 128x128 block, 4 waves x (4x4 of 16x16x32 MFMA). Double-buffered
// global_load_lds staging: stage k+1 into buf^1 during MFMA on buf,
// single barrier per K-step (vmcnt(0) drain lands after compute).
// EPI: 0 = fp32 store, 1 = softplus(v + bias[col]) fp32, 2 = bf16 store.
template <int EPI>
__global__ __launch_bounds__(256)
void gemm_mfma(const ushort* __restrict__ A, const ushort* __restrict__ Bm,
               const float* __restrict__ bias, void* __restrict__ Cout,
               int N, int K)
{
    __shared__ __attribute__((aligned(16))) ushort As[2][4096];  // 16 KB
    __shared__ __attribute__((aligned(16))) ushort Bs[2][4096];  // 16 KB

    const int tid  = threadIdx.x;
    const int lane = tid & 63;
    const int wave = tid >> 6;
    const int wm   = (wave >> 1) * 64;
    const int wn   = (wave & 1) * 64;
    const int row0 = blockIdx.y * 128;
    const int col0 = blockIdx.x * 128;

    // staging: lane t writes LDS bytes wave*1024 + lane*16 within each
    // half-tile (rows tid/4, slot tid&3). Slot c holds global chunk
    // q = (c - (row>>1)) & 3 so the LDS image matches lds_addr().
    const int crow = tid >> 2;            // 0..63 (row within half-tile)
    const int cq   = tid & 3;             // LDS slot
    const int qsrc = (cq - (crow >> 1)) & 3;   // global 16B chunk to fetch
    const ushort* Ag0 = A  + (size_t)(row0 + crow) * K + qsrc * 8;
    const ushort* Ag1 = A  + (size_t)(row0 + crow + 64) * K + qsrc * 8;
    const ushort* Bg0 = Bm + (size_t)(col0 + crow) * K + qsrc * 8;
    const ushort* Bg1 = Bm + (size_t)(col0 + crow + 64) * K + qsrc * 8;

    const int wbase = wave * 512;   // ushort units

    const int flo = lds_frag_off(lane);
    const int fra = (wm << 5) + flo;
    const int frb = (wn << 5) + flo;

    f32x4 acc[4][4];
#pragma unroll
    for (int mi = 0; mi < 4; ++mi)
#pragma unroll
        for (int ni = 0; ni < 4; ++ni)
            acc[mi][ni] = (f32x4){0.f, 0.f, 0.f, 0.f};

    // prologue: stage tile 0 into buffer 0, drain.
    gload16(Ag0, As[0] + wbase);
    gload16(Ag1, As[0] + 2048 + wbase);
    gload16(Bg0, Bs[0] + wbase);
    gload16(Bg1, Bs[0] + 2048 + wbase);
    __syncthreads();

    int cur = 0;
    for (int k0 = 0; k0 < K; k0 += 32) {
        const int nxt = cur ^ 1;
        if (k0 + 32 < K) {                 // issue next-tile loads first
            gload16(Ag0 + k0 + 32, As[nxt] + wbase);
            gload16(Ag1 + k0 + 32, As[nxt] + 2048 + wbase);
            gload16(Bg0 + k0 + 32, Bs[nxt] + wbase);
            gload16(Bg1 + k0 + 32, Bs[nxt] + 2048 + wbase);
        }
        const ushort* Ac = As[cur];
        const ushort* Bc = Bs[cur];
        bf16x8 af[4], bf[4];
#pragma unroll
        for (int mi = 0; mi < 4; ++mi)
            af[mi] = *(const bf16x8*)(Ac + fra + mi * 512);
#pragma unroll
        for (int ni = 0; ni < 4; ++ni)
            bf[ni] = *(const bf16x8*)(Bc + frb + ni * 512);
#pragma unroll
        for (int mi = 0; mi < 4; ++mi)
#pragma unroll
            for (int ni = 0; ni < 4; ++ni)
                acc[mi][ni] = __builtin_amdgcn_mfma_f32_16x16x32_bf16(
                    af[mi], bf[ni], acc[mi][ni], 0, 0, 0);
        __syncthreads();                   // drains vmcnt -> buf[nxt] ready
        cur = nxt;
    }

#pragma unroll
    for (int mi = 0; mi < 4; ++mi) {
        const int rg = row0 + wm + mi * 16 + (lane >> 4) * 4;
#pragma unroll
        for (int ni = 0; ni < 4; ++ni) {
            const int cg = col0 + wn + ni * 16 + (lane & 15);
            f32x4 v = acc[mi][ni];
            if (EPI == 1) {
                const float bv = bias[cg];
#pragma unroll
                for (int r = 0; r < 4; ++r) v[r] = softplus_f(v[r] + bv);
            }
#pragma unroll
            for (int r = 0; r < 4; ++r) {
                if (EPI == 2)
                    ((ushort*)Cout)[(size_t)(rg + r) * N + cg] = f2bf(v[r]);
                else
                    ((float*)Cout)[(size_t)(rg + r) * N + cg] = v[r];
            }
        }
    }
}

// Split-K bc GEMM: part[ks] = xc[:, ks*256:(ks+1)*256] @ Wx^T slice.
__global__ __launch_bounds__(256)
void gemm_bc_mfma(const ushort* __restrict__ A, const ushort* __restrict__ Bh,
                  const ushort* __restrict__ Bl, float* __restrict__ part)
{
    __shared__ __attribute__((aligned(16))) ushort As[4096];
    __shared__ __attribute__((aligned(16))) ushort Bhs[1024];
    __shared__ __attribute__((aligned(16))) ushort Bls[1024];

    const int tid  = threadIdx.x;
    const int lane = tid & 63;
    const int wave = tid >> 6;
    const int ks   = blockIdx.x;     // 0..7
    const int mb   = blockIdx.y;     // 0..63
    const int row0 = mb * 128;
    const int kb   = ks * 256;

    const int crow = tid >> 2;
    const int cq   = tid & 3;
    const ushort* Ag0 = A + (size_t)(row0 + crow) * 2048 + kb + cq * 8;
    const ushort* Ag1 = A + (size_t)(row0 + crow + 64) * 2048 + kb + cq * 8;
    const int st0 = lds_addr(crow, cq);
    const int st1 = st0 + 2048;

    const int t2   = tid & 127;
    const int brow = t2 >> 2;        // 0..31
    const int bq   = t2 & 3;
    const ushort* Bg = (tid < 128 ? Bh : Bl) + (size_t)brow * 2048 + kb + bq * 8;
    ushort* Bdst     = (tid < 128 ? Bhs : Bls) + lds_addr(brow, bq);

    const int wm  = wave * 32;
    const int flo = lds_frag_off(lane);
    const int fra = (wm << 5) + flo;
    const int frb = flo;

    f32x4 acc[2][2];
#pragma unroll
    for (int mi = 0; mi < 2; ++mi)
#pragma unroll
        for (int ni = 0; ni < 2; ++ni)
            acc[mi][ni] = (f32x4){0.f, 0.f, 0.f, 0.f};

    uint4 ra0 = *(const uint4*)Ag0, ra1 = *(const uint4*)Ag1;
    uint4 rb  = *(const uint4*)Bg;

    for (int kt = 0; kt < 8; ++kt) {
        __syncthreads();
        *(uint4*)(As + st0) = ra0;
        *(uint4*)(As + st1) = ra1;
        *(uint4*)Bdst = rb;
        __syncthreads();
        if (kt < 7) {
            ra0 = *(const uint4*)(Ag0 + (kt + 1) * 32);
            ra1 = *(const uint4*)(Ag1 + (kt + 1) * 32);
            rb  = *(const uint4*)(Bg + (kt + 1) * 32);
        }
        bf16x8 af[2], bhf[2], blf[2];
#pragma unroll
        for (int mi = 0; mi < 2; ++mi)
            af[mi] = *(const bf16x8*)(As + fra + mi * 512);
#pragma unroll
        for (int ni = 0; ni < 2; ++ni) {
            bhf[ni] = *(const bf16x8*)(Bhs + frb + ni * 512);
            blf[ni] = *(const bf16x8*)(Bls + frb + ni * 512);
        }
#pragma unroll
        for (int mi = 0; mi < 2; ++mi)
#pragma unroll
            for (int ni = 0; ni < 2; ++ni) {
                acc[mi][ni] = __builtin_amdgcn_mfma_f32_16x16x32_bf16(
                    af[mi], bhf[ni], acc[mi][ni], 0, 0, 0);
                acc[mi][ni] = __builtin_amdgcn_mfma_f32_16x16x32_bf16(
                    af[mi], blf[ni], acc[mi][ni], 0, 0, 0);
            }
    }

#pragma unroll
    for (int mi = 0; mi < 2; ++mi) {
        const int rg = row0 + wm + mi * 16 + (lane >> 4) * 4;
#pragma unroll
        for (int ni = 0; ni < 2; ++ni) {
            const int cg = ni * 16 + (lane & 15);
            f32x4 v = acc[mi][ni];
#pragma unroll
            for (int r = 0; r < 4; ++r)
                part[((size_t)ks * 8192 + rg + r) * 32 + cg] = v[r];
        }
    }
}

__global__ __launch_bounds__(256)
void bc_reduce_kernel(const float* __restrict__ part, float* __restrict__ bc)
{
    const int i = blockIdx.x * 256 + threadIdx.x;   // 262144
    float s = 0.f;
#pragma unroll
    for (int ks = 0; ks < 8; ++ks)
        s += part[(size_t)ks * 262144 + i];
    bc[i] = s;
}

// Depthwise causal conv1d (4 taps) + bias + silu; bf16 in, bf16 out.
__global__ __launch_bounds__(256)
void conv_silu_kernel(const ushort* __restrict__ xi, const float* __restrict__ cw,
                      const float* __restrict__ cb, ushort* __restrict__ xc)
{
    const int idx = blockIdx.x * 256 + threadIdx.x;
    const int e   = (idx & 511) << 2;
    const int row = idx >> 9;
    const int l   = row & 2047;

    const float4 w0 = *(const float4*)(cw + (size_t)(e + 0) * 4);
    const float4 w1 = *(const float4*)(cw + (size_t)(e + 1) * 4);
    const float4 w2 = *(const float4*)(cw + (size_t)(e + 2) * 4);
    const float4 w3 = *(const float4*)(cw + (size_t)(e + 3) * 4);

    float4 acc = *(const float4*)(cb + e);

#define CONV_TAP(K_, WSEL)                                                  \
    {                                                                       \
        ushort4 t = *(const ushort4*)(xi + (size_t)(row - (K_)) * 2048 + e);\
        acc.x = fmaf(bf2f(t.x), w0.WSEL, acc.x);                            \
        acc.y = fmaf(bf2f(t.y), w1.WSEL, acc.y);                            \
        acc.z = fmaf(bf2f(t.z), w2.WSEL, acc.z);                            \
        acc.w = fmaf(bf2f(t.w), w3.WSEL, acc.w);                            \
    }
    if (l >= 3) CONV_TAP(3, x)
    if (l >= 2) CONV_TAP(2, y)
    if (l >= 1) CONV_TAP(1, z)
    CONV_TAP(0, w)
#undef CONV_TAP

    ushort4 o;
    o.x = f2bf(silu_f(acc.x)); o.y = f2bf(silu_f(acc.y));
    o.z = f2bf(silu_f(acc.z)); o.w = f2bf(silu_f(acc.w));
    *(ushort4*)(xc + (size_t)row * 2048 + e) = o;
}

// ---- d-parallel chunked selective scan (NCHK chunks of CLEN) ----

// Pass 1: chunks 0..NCHK-2, h from 0, writes he + P = exp(A * sum dt).
// B panel for the chunk staged in LDS (broadcast reads, no L2 dep chain).
__global__ __launch_bounds__(256)
void scan_part1(const ushort* __restrict__ xcb, const float* __restrict__ dbuf,
                const float* __restrict__ bcbuf, const float* __restrict__ A_log,
                float* __restrict__ sum_h, float* __restrict__ sum_p)
{
    __shared__ float bcs[CLEN * 32];           // 8 KB

    const int c    = blockIdx.x >> 5;          // 0..NCHK-2
    const int b    = (blockIdx.x >> 3) & 3;
    const int dblk = blockIdx.x & 7;
    const int d    = dblk * 256 + threadIdx.x;

    const size_t row0 = (size_t)b * 2048 + (size_t)c * CLEN;
    const float* bcp  = bcbuf + row0 * 32;

    // cooperative stage of the chunk's B/C panel (CLEN*32 floats)
#pragma unroll
    for (int i = 0; i < (CLEN * 32) / (4 * 256); ++i)
        ((float4*)bcs)[threadIdx.x + i * 256] =
            ((const float4*)bcp)[threadIdx.x + i * 256];

    float Aval[16];
#pragma unroll
    for (int q = 0; q < 4; ++q) {
        float4 al = *(const float4*)(A_log + (size_t)d * 16 + q * 4);
        Aval[q*4+0] = -__expf(al.x); Aval[q*4+1] = -__expf(al.y);
        Aval[q*4+2] = -__expf(al.z); Aval[q*4+3] = -__expf(al.w);
    }

    const float*  dp = dbuf + row0 * 2048 + d;
    const ushort* xp = xcb  + row0 * 2048 + d;

    float h[16];
#pragma unroll
    for (int s = 0; s < 16; ++s) h[s] = 0.f;
    float S = 0.f;

    float wdt[SW], wxv[SW];
#pragma unroll
    for (int j = 0; j < SW; ++j) {
        wdt[j] = dp[(size_t)j * 2048];
        wxv[j] = bf2f(xp[(size_t)j * 2048]);
    }
    __syncthreads();

    for (int l0 = 0; l0 < CLEN; l0 += SW) {
        float ndt[SW], nxv[SW];
        const bool more = (l0 + SW) < CLEN;
        if (more) {
#pragma unroll
            for (int j = 0; j < SW; ++j) {
                const size_t o = (size_t)(l0 + SW + j);
                ndt[j] = dp[o * 2048];
                nxv[j] = bf2f(xp[o * 2048]);
            }
        }
#pragma unroll
        for (int j = 0; j < SW; ++j) {
            const int l = l0 + j;
            const float dt = wdt[j];
            const float t  = dt * wxv[j];
            S += dt;
#pragma unroll
            for (int s = 0; s < 16; ++s)
                h[s] = __expf(dt * Aval[s]) * h[s] + bcs[l * 32 + s] * t;
        }
        if (more) {
#pragma unroll
            for (int j = 0; j < SW; ++j) { wdt[j] = ndt[j]; wxv[j] = nxv[j]; }
        }
    }

    float* sh = sum_h + ((((size_t)c * 4 + b) * 2048 + d) << 4);
    float* sp = sum_p + ((((size_t)c * 4 + b) * 2048 + d) << 4);
#pragma unroll
    for (int q = 0; q < 4; ++q) {
        *(float4*)(sh + q * 4) = make_float4(h[q*4], h[q*4+1], h[q*4+2], h[q*4+3]);
        *(float4*)(sp + q * 4) = make_float4(__expf(Aval[q*4] * S), __expf(Aval[q*4+1] * S),
                                             __expf(Aval[q*4+2] * S), __expf(Aval[q*4+3] * S));
    }
}

// Sequential prefix over chunk summaries, in-place into sum_h.
// After: sum_h slot c holds the scan state at the START of chunk c+1.
// Grid: 32 blocks (4 b x 8 dblk) x 256 threads; NCHK-1 dependent steps.
__global__ __launch_bounds__(256)
void scan_fold(float* __restrict__ sum_h, const float* __restrict__ sum_p)
{
    const int b = blockIdx.x >> 3;
    const int d = (blockIdx.x & 7) * 256 + threadIdx.x;

    float h[16];
#pragma unroll
    for (int s = 0; s < 16; ++s) h[s] = 0.f;

    for (int c = 0; c < NCHK - 1; ++c) {
        float*       sh = sum_h + ((((size_t)c * 4 + b) * 2048 + d) << 4);
        const float* sp = sum_p + ((((size_t)c * 4 + b) * 2048 + d) << 4);
#pragma unroll
        for (int q = 0; q < 4; ++q) {
            float4 vh = *(const float4*)(sh + q * 4);
            float4 vp = *(const float4*)(sp + q * 4);
            h[q*4+0] = vh.x + vp.x * h[q*4+0];
            h[q*4+1] = vh.y + vp.y * h[q*4+1];
            h[q*4+2] = vh.z + vp.z * h[q*4+2];
            h[q*4+3] = vh.w + vp.w * h[q*4+3];
        }
#pragma unroll
        for (int q = 0; q < 4; ++q)
            *(float4*)(sh + q * 4) = make_float4(h[q*4], h[q*4+1], h[q*4+2], h[q*4+3]);
    }
}

// Pass 2: all NCHK chunks; load start state (sum_h[c-1]), scan, y bf16 out.
// B/C panel for the chunk staged in LDS.
__global__ __launch_bounds__(256)
void scan_part2(const ushort* __restrict__ zbuf, const ushort* __restrict__ xcb,
                const float* __restrict__ dbuf, const float* __restrict__ bcbuf,
                const float* __restrict__ A_log, const float* __restrict__ Dp,
                const float* __restrict__ sum_h, ushort* __restrict__ ybuf)
{
    __shared__ float bcs[CLEN * 32];           // 8 KB

    const int c    = blockIdx.x >> 5;          // 0..NCHK-1
    const int b    = (blockIdx.x >> 3) & 3;
    const int dblk = blockIdx.x & 7;
    const int d    = dblk * 256 + threadIdx.x;

    const size_t row0 = (size_t)b * 2048 + (size_t)c * CLEN;
    const float* bcp  = bcbuf + row0 * 32;

#pragma unroll
    for (int i = 0; i < (CLEN * 32) / (4 * 256); ++i)
        ((float4*)bcs)[threadIdx.x + i * 256] =
            ((const float4*)bcp)[threadIdx.x + i * 256];

    float Aval[16];
#pragma unroll
    for (int q = 0; q < 4; ++q) {
        float4 al = *(const float4*)(A_log + (size_t)d * 16 + q * 4);
        Aval[q*4+0] = -__expf(al.x); Aval[q*4+1] = -__expf(al.y);
        Aval[q*4+2] = -__expf(al.z); Aval[q*4+3] = -__expf(al.w);
    }
    const float Dv = Dp[d];

    float h[16];
    if (c == 0) {
#pragma unroll
        for (int s = 0; s < 16; ++s) h[s] = 0.f;
    } else {
        const float* sh = sum_h + ((((size_t)(c - 1) * 4 + b) * 2048 + d) << 4);
#pragma unroll
        for (int q = 0; q < 4; ++q)
            *(float4*)&h[q*4] = *(const float4*)(sh + q * 4);
    }

    const float*  dp = dbuf + row0 * 2048 + d;
    const ushort* xp = xcb  + row0 * 2048 + d;
    const ushort* zp = zbuf + row0 * 2048 + d;
    ushort*       yp = ybuf + row0 * 2048 + d;

    float wdt[SW], wxv[SW], wzv[SW];
#pragma unroll
    for (int j = 0; j < SW; ++j) {
        wdt[j] = dp[(size_t)j * 2048];
        wxv[j] = bf2f(xp[(size_t)j * 2048]);
        wzv[j] = bf2f(zp[(size_t)j * 2048]);
    }
    __syncthreads();

    for (int l0 = 0; l0 < CLEN; l0 += SW) {
        float ndt[SW], nxv[SW], nzv[SW];
        const bool more = (l0 + SW) < CLEN;
        if (more) {
#pragma unroll
            for (int j = 0; j < SW; ++j) {
                const size_t o = (size_t)(l0 + SW + j);
                ndt[j] = dp[o * 2048];
                nxv[j] = bf2f(xp[o * 2048]);
                nzv[j] = bf2f(zp[o * 2048]);
            }
        }
#pragma unroll
        for (int j = 0; j < SW; ++j) {
            const int l = l0 + j;
            const float dt = wdt[j];
            const float t  = dt * wxv[j];
#pragma unroll
            for (int s = 0; s < 16; ++s)
                h[s] = __expf(dt * Aval[s]) * h[s] + bcs[l * 32 + s] * t;
            float y0 = 0.f, y1 = 0.f, y2 = 0.f, y3 = 0.f;
#pragma unroll
            for (int s = 0; s < 16; s += 4) {
                y0 = fmaf(h[s+0], bcs[l * 32 + 16 + s + 0], y0);
                y1 = fmaf(h[s+1], bcs[l * 32 + 16 + s + 1], y1);
                y2 = fmaf(h[s+2], bcs[l * 32 + 16 + s + 2], y2);
                y3 = fmaf(h[s+3], bcs[l * 32 + 16 + s + 3], y3);
            }
            float y = (y0 + y1) + (y2 + y3) + Dv * wxv[j];
            yp[(size_t)l * 2048] = f2bf(y * silu_f(wzv[j]));
        }
        if (more) {
#pragma unroll
            for (int j = 0; j < SW; ++j) {
                wdt[j] = ndt[j]; wxv[j] = nxv[j]; wzv[j] = nzv[j];
            }
        }
    }
}

extern "C" void kernel_launch(void* const* d_in, const int* in_sizes, int n_in,
                              void* d_out, int out_size, void* d_ws, size_t ws_size,
                              hipStream_t stream)
{
    const float* x          = (const float*)d_in[0];
    const float* in_proj_w  = (const float*)d_in[1];
    const float* conv_w     = (const float*)d_in[2];
    const float* conv_b     = (const float*)d_in[3];
    const float* x_proj_w   = (const float*)d_in[4];
    const float* dt_proj_w  = (const float*)d_in[5];
    const float* dt_proj_b  = (const float*)d_in[6];
    const float* A_log      = (const float*)d_in[7];
    const float* Dp         = (const float*)d_in[8];
    const float* out_proj_w = (const float*)d_in[9];
    float* out = (float*)d_out;

    // Workspace (~232 MB of 256 MiB)
    ushort* XI    = (ushort*)d_ws;                    // 32 MB; later Y'
    ushort* Z     = XI + 16777216;                    // 32 MB
    ushort* XC2   = Z + 16777216;                     // 32 MB
    float*  DELTA = (float*)(XC2 + 16777216);         // 64 MB
    ushort* XP    = (ushort*)DELTA;                   // x' bf16 (pre-DELTA)
    ushort* WINH  = (ushort*)(DELTA + 16777216);      // 8 MB [4096,1024] bf16
    ushort* WDTH  = WINH + 4194304;                   // 8 MB [2048,2048] bf16
    ushort* WOUTH = WDTH + 4194304;                   // 4 MB [1024,2048] bf16
    float*  BC    = (float*)(WOUTH + 2097152);        // 1 MB
    float*  SUMH  = BC + 262144;                      // 16.8 MB (32*4*2048*16)
    float*  SUMP  = SUMH + 4194304;                   // 16.8 MB
    ushort* XPH   = (ushort*)(SUMP + 4194304);        // 128 KB (x_proj hi)
    ushort* XPL   = XPH + 65536;                      // 128 KB
    float*  PART  = (float*)(XPL + 65536);            // 8 MB split-K partials
    ushort* Yp    = XI;

    const dim3 blk(256);

    // 0) conversions (weights plain bf16 except x_proj hi/lo)
    cvt_bf16_kernel<<<dim3(8192), blk, 0, stream>>>(x, XP);
    cvt_bf16_kernel<<<dim3(4096), blk, 0, stream>>>(in_proj_w, WINH);
    cvt_bf16_kernel<<<dim3(4096), blk, 0, stream>>>(dt_proj_w, WDTH);
    cvt_bf16_kernel<<<dim3(2048), blk, 0, stream>>>(out_proj_w, WOUTH);
    split_w_kernel<<<dim3(64),    blk, 0, stream>>>(x_proj_w, XPH, XPL);

    // 1) xi, z
    gemm_mfma<2><<<dim3(16, 64), blk, 0, stream>>>(XP, WINH, nullptr, XI, 2048, 1024);
    gemm_mfma<2><<<dim3(16, 64), blk, 0, stream>>>(XP, WINH + 2097152, nullptr, Z, 2048, 1024);

    // 2) xc = silu(conv(xi) + b)
    conv_silu_kernel<<<dim3(16384), blk, 0, stream>>>(XI, conv_w, conv_b, XC2);

    // 3) delta = softplus(xc @ Wdt^T + b)
    gemm_mfma<1><<<dim3(16, 64), blk, 0, stream>>>(XC2, WDTH, dt_proj_b, DELTA, 2048, 2048);

    // 4) bc = xc @ x_proj_w^T  (split-K MFMA + reduce)
    gemm_bc_mfma<<<dim3(8, 64), blk, 0, stream>>>(XC2, XPH, XPL, PART);
    bc_reduce_kernel<<<dim3(1024), blk, 0, stream>>>(PART, BC);

    // 5) chunked scan: pass1 -> prefix fold -> pass2
    scan_part1<<<dim3((NCHK - 1) * 32), blk, 0, stream>>>(XC2, DELTA, BC, A_log, SUMH, SUMP);
    scan_fold<<<dim3(32), blk, 0, stream>>>(SUMH, SUMP);
    scan_part2<<<dim3(NCHK * 32), blk, 0, stream>>>(Z, XC2, DELTA, BC, A_log, Dp,
                                                    SUMH, Yp);

    // 6) out = y @ Wout^T
    gemm_mfma<0><<<dim3(8, 64), blk, 0, stream>>>(Yp, WOUTH, nullptr, out, 1024, 2048);
}